// Round 15
// baseline (282.120 us; speedup 1.0000x reference)
//
#include <hip/hip_runtime.h>
#include <math.h>

#define N_NODES 50000
#define N_EDGES 800000
#define D_IN    128
#define D_H     32
#define N_HEADS 8
#define N_GRAPHS 512
#define E_TOT   (N_EDGES + N_NODES)      // 850000 (with self-loops)
#define HDIM    (N_HEADS * D_H)          // 256
#define NEG_SLOPE 0.2f
#define NSCAN_BLK ((N_NODES + 255) / 256)   // 196
#define LOG2E 1.4426950408889634f
#define RESCALE_THR2 11.0f               // ~8 nats in log2 units

typedef short bfrag8 __attribute__((ext_vector_type(8)));   // 8 bf16 = 4 VGPRs
typedef float f32x4 __attribute__((ext_vector_type(4)));
typedef float f32x2 __attribute__((ext_vector_type(2)));

#if __has_builtin(__builtin_amdgcn_exp2f)
#define EXP2(x) __builtin_amdgcn_exp2f(x)
#else
#define EXP2(x) exp2f(x)
#endif

// ---- bf16 helpers ----
__device__ __forceinline__ unsigned short f2b(float x) {
    unsigned u = __float_as_uint(x);
    unsigned r = u + 0x7FFFu + ((u >> 16) & 1u);   // round-to-nearest-even
    return (unsigned short)(r >> 16);
}
__device__ __forceinline__ f32x2 b2x2(unsigned u) {
    f32x2 v;
    v.x = __uint_as_float(u << 16);
    v.y = __uint_as_float(u & 0xFFFF0000u);
    return v;
}

// ---- 8-lane sum via DPP (VALU-only; no LDS pipe / lgkmcnt) ----
__device__ __forceinline__ float dpp8_sum(float x) {
    x += __int_as_float(__builtin_amdgcn_mov_dpp(__float_as_int(x), 0xB1, 0xF, 0xF, true));
    x += __int_as_float(__builtin_amdgcn_mov_dpp(__float_as_int(x), 0x4E, 0xF, 0xF, true));
    x += __int_as_float(__builtin_amdgcn_mov_dpp(__float_as_int(x), 0x141, 0xF, 0xF, true));
    return x;
}

// ==== fused front kernel: reduce_sum | hist(+rank) | weight panels ====
#define RS_BLK   512
#define HIST_BLK ((E_TOT + 255) / 256)       // 3321
#define W1_BLK   (512 * 128 / 256)           // 256
#define W2_BLK   (64 * 256 / 256)            // 64
__global__ void k_front(const float* __restrict__ ew, const int* __restrict__ ei,
                        const float* __restrict__ Wl1, const float* __restrict__ Wr1,
                        const float* __restrict__ Wl2, const float* __restrict__ Wr2,
                        float* __restrict__ fillsum, int* __restrict__ deg,
                        int* __restrict__ rank,
                        unsigned short* __restrict__ Wt1,
                        unsigned short* __restrict__ Wt2) {
    __shared__ float ls[4];
    int b = blockIdx.x;
    if (b < RS_BLK) {
        int t = b * 256 + threadIdx.x;
        float s = 0.f;
        for (int i = t; i < N_EDGES; i += RS_BLK * 256) s += ew[i];
        for (int m = 1; m < 64; m <<= 1) s += __shfl_xor(s, m);
        int lane = threadIdx.x & 63, wv = threadIdx.x >> 6;
        if (lane == 0) ls[wv] = s;
        __syncthreads();
        if (threadIdx.x == 0) atomicAdd(fillsum, ls[0] + ls[1] + ls[2] + ls[3]);
    } else if (b < RS_BLK + HIST_BLK) {
        int e = (b - RS_BLK) * 256 + threadIdx.x;
        if (e >= E_TOT) return;
        int dst = (e < N_EDGES) ? ei[N_EDGES + e] : (e - N_EDGES);
        rank[e] = atomicAdd(&deg[dst], 1);   // rank is free: atomic returns old
    } else if (b < RS_BLK + HIST_BLK + W1_BLK) {
        int t = (b - RS_BLK - HIST_BLK) * 256 + threadIdx.x;   // t = c*128 + k
        int c = t >> 7, k = t & 127;
        float v = (c < 256) ? Wl1[k * 256 + c] : Wr1[k * 256 + (c - 256)];
        Wt1[t] = f2b(v);
    } else {
        int t = (b - RS_BLK - HIST_BLK - W1_BLK) * 256 + threadIdx.x;   // t = c*256 + k
        int c = t >> 8, k = t & 255;
        float v = (c < 32) ? Wl2[k * 32 + c] : Wr2[k * 32 + (c - 32)];
        Wt2[t] = f2b(v);
    }
}

// ---- CSR scan (exclusive), 3-kernel version ----
__global__ void k_scan1(const int* __restrict__ deg, int* __restrict__ start,
                        int* __restrict__ bsum) {
    __shared__ int sh[256];
    int i = blockIdx.x * 256 + threadIdx.x;
    int v = (i < N_NODES) ? deg[i] : 0;
    sh[threadIdx.x] = v;
    __syncthreads();
    for (int o = 1; o < 256; o <<= 1) {
        int t = (threadIdx.x >= o) ? sh[threadIdx.x - o] : 0;
        __syncthreads();
        sh[threadIdx.x] += t;
        __syncthreads();
    }
    if (i < N_NODES) start[i] = sh[threadIdx.x] - v;
    if (threadIdx.x == 255) bsum[blockIdx.x] = sh[255];
}
__global__ void k_scan2(int* __restrict__ bsum, int nb) {
    __shared__ int sh[256];
    int v = (threadIdx.x < nb) ? bsum[threadIdx.x] : 0;
    sh[threadIdx.x] = v;
    __syncthreads();
    for (int o = 1; o < 256; o <<= 1) {
        int t = (threadIdx.x >= o) ? sh[threadIdx.x - o] : 0;
        __syncthreads();
        sh[threadIdx.x] += t;
        __syncthreads();
    }
    if (threadIdx.x < nb) bsum[threadIdx.x] = sh[threadIdx.x] - v;
}
// finalizes start[] and writes csr slack entries for unguarded prefetch
__global__ void k_scan3(int* __restrict__ start, const int* __restrict__ bsum,
                        int2* __restrict__ csr) {
    int i = blockIdx.x * 256 + threadIdx.x;
    if (i < N_NODES) start[i] += bsum[blockIdx.x];
    if (i == 0) {
        #pragma unroll
        for (int k = 0; k < 8; ++k) csr[E_TOT + k] = make_int2(0, 0);
    }
}

// ==== hybrid: GEMM1 (128x128 tile, fused f32->bf16 cast) || atomic-free scatter ====
#define G1_BLOCKS 1564                       // 4 cols x 391 row-blocks
#define SC_BLOCKS ((E_TOT + 255) / 256)      // 3321
#define HY_TOT    4985
__global__ __launch_bounds__(256) void k_gemm1_scatter(
    const float* __restrict__ A, const unsigned short* __restrict__ Bt,
    unsigned short* __restrict__ C,
    const int* __restrict__ ei, const float* __restrict__ ew,
    const float* __restrict__ fillsum, const int* __restrict__ start,
    const int* __restrict__ rank, int2* __restrict__ csr)
{
    const int KC = 128, NN = 512, M = N_NODES;
    __shared__ unsigned short A_lds[128][KC + 8];
    __shared__ unsigned short B_lds[128][KC + 8];
    int bid = blockIdx.x;
    int tid = threadIdx.x;
    if (bid % 3 != 0) {
        // ---- scatter part: pos from precomputed rank, NO atomics ----
        int sid = bid - bid / 3 - 1;
        if (sid >= SC_BLOCKS) return;
        int e = sid * 256 + tid;
        if (e >= E_TOT) return;
        int src, dst; float w;
        if (e < N_EDGES) { src = ei[e]; dst = ei[N_EDGES + e]; w = ew[e]; }
        else { src = dst = e - N_EDGES; w = fillsum[0] * (1.0f / N_EDGES); }
        int pos = start[dst] + rank[e];
        csr[pos] = make_int2(src, __float_as_int(w));
        return;
    }
    int gid = bid / 3;
    if (gid >= G1_BLOCKS) return;
    int row0 = (gid >> 2) * 128, col0 = (gid & 3) * 128;
    for (int idx = tid; idx < 128 * 32; idx += 256) {
        int r = idx >> 5, c4 = idx & 31;
        int gr = row0 + r;
        float4 v = {0.f, 0.f, 0.f, 0.f};
        if (gr < M) v = ((const float4*)(A + (size_t)gr * KC))[c4];
        ushort4 o;
        o.x = f2b(v.x); o.y = f2b(v.y); o.z = f2b(v.z); o.w = f2b(v.w);
        *(ushort4*)&A_lds[r][c4 * 4] = o;
    }
    for (int idx = tid; idx < 128 * 16; idx += 256) {
        int r = idx >> 4, ch = idx & 15;
        uint4 v = *(const uint4*)(Bt + (size_t)(col0 + r) * KC + ch * 8);
        *(uint4*)&B_lds[r][ch * 8] = v;
    }
    __syncthreads();

    int wid = tid >> 6, lane = tid & 63;
    int wy = wid >> 1, wx = wid & 1;
    int lr = lane & 15, lh = lane >> 4;
    f32x4 acc[4][4] = {};
    #pragma unroll
    for (int k0 = 0; k0 < KC; k0 += 32) {
        bfrag8 af[4], bf[4];
        #pragma unroll
        for (int i = 0; i < 4; ++i) {
            af[i] = *(const bfrag8*)&A_lds[64 * wy + 16 * i + lr][k0 + lh * 8];
            bf[i] = *(const bfrag8*)&B_lds[64 * wx + 16 * i + lr][k0 + lh * 8];
        }
        #pragma unroll
        for (int mi = 0; mi < 4; ++mi)
            #pragma unroll
            for (int ni = 0; ni < 4; ++ni)
                acc[mi][ni] = __builtin_amdgcn_mfma_f32_16x16x32_bf16(af[mi], bf[ni], acc[mi][ni], 0, 0, 0);
    }
    #pragma unroll
    for (int mi = 0; mi < 4; ++mi) {
        #pragma unroll
        for (int ni = 0; ni < 4; ++ni) {
            #pragma unroll
            for (int r = 0; r < 4; ++r) {
                int row = row0 + 64 * wy + 16 * mi + lh * 4 + r;
                if (row < M)
                    C[(size_t)row * NN + col0 + 64 * wx + 16 * ni + lr] = f2b(acc[mi][ni][r]);
            }
        }
    }
}

// ---- GEMM2: 64x64 tile, bf16 MFMA: C[M,64] = A[M,256] * Bt[64,256]^T ----
__global__ __launch_bounds__(256) void k_gemm2(
    const unsigned short* __restrict__ A, const unsigned short* __restrict__ Bt,
    unsigned short* __restrict__ C, int M)
{
    const int KC = 256, NN = 64;
    __shared__ unsigned short A_lds[64][KC + 8];
    __shared__ unsigned short B_lds[64][KC + 8];
    int row0 = blockIdx.y * 64, col0 = 0;
    int tid = threadIdx.x;
    const int CPR = KC / 8;
    for (int idx = tid; idx < 64 * CPR; idx += 256) {
        int r = idx / CPR, ch = idx % CPR;
        int gr = row0 + r;
        uint4 v = {0u, 0u, 0u, 0u};
        if (gr < M) v = *(const uint4*)(A + (size_t)gr * KC + ch * 8);
        *(uint4*)&A_lds[r][ch * 8] = v;
    }
    for (int idx = tid; idx < 64 * CPR; idx += 256) {
        int r = idx / CPR, ch = idx % CPR;
        uint4 v = *(const uint4*)(Bt + (size_t)(col0 + r) * KC + ch * 8);
        *(uint4*)&B_lds[r][ch * 8] = v;
    }
    __syncthreads();

    int wid = tid >> 6, lane = tid & 63;
    int wy = wid >> 1, wx = wid & 1;
    int lr = lane & 15, lh = lane >> 4;
    f32x4 acc[2][2] = {};
    #pragma unroll
    for (int k0 = 0; k0 < KC; k0 += 32) {
        bfrag8 a0 = *(const bfrag8*)&A_lds[32 * wy + lr][k0 + lh * 8];
        bfrag8 a1 = *(const bfrag8*)&A_lds[32 * wy + 16 + lr][k0 + lh * 8];
        bfrag8 b0 = *(const bfrag8*)&B_lds[32 * wx + lr][k0 + lh * 8];
        bfrag8 b1 = *(const bfrag8*)&B_lds[32 * wx + 16 + lr][k0 + lh * 8];
        acc[0][0] = __builtin_amdgcn_mfma_f32_16x16x32_bf16(a0, b0, acc[0][0], 0, 0, 0);
        acc[0][1] = __builtin_amdgcn_mfma_f32_16x16x32_bf16(a0, b1, acc[0][1], 0, 0, 0);
        acc[1][0] = __builtin_amdgcn_mfma_f32_16x16x32_bf16(a1, b0, acc[1][0], 0, 0, 0);
        acc[1][1] = __builtin_amdgcn_mfma_f32_16x16x32_bf16(a1, b1, acc[1][1], 0, 0, 0);
    }
    #pragma unroll
    for (int mt = 0; mt < 2; ++mt) {
        #pragma unroll
        for (int nt = 0; nt < 2; ++nt) {
            #pragma unroll
            for (int r = 0; r < 4; ++r) {
                int row = row0 + 32 * wy + 16 * mt + lh * 4 + r;
                if (row < M)
                    C[(size_t)row * NN + col0 + 32 * wx + 16 * nt + lr] = f2b(acc[mt][nt][r]);
            }
        }
    }
}

// ---- fused layer-1: one wave per node; lane owns 4 of 256 channels ----
// 4-edge unroll, unguarded prefetch (slack entries), DPP reduce, log2 softmax.
__global__ __launch_bounds__(256) void k_gat1(
    const unsigned short* __restrict__ xlr,
    const int* __restrict__ start, const int* __restrict__ deg,
    const int2* __restrict__ csr,
    const float* __restrict__ We, const float* __restrict__ att,
    const float* __restrict__ b1, unsigned short* __restrict__ out1)
{
    int wid = (blockIdx.x * blockDim.x + threadIdx.x) >> 6;
    int lane = threadIdx.x & 63;
    if (wid >= N_NODES) return;
    f32x2 we01 = ((const f32x2*)We)[2 * lane],  we23 = ((const f32x2*)We)[2 * lane + 1];
    f32x2 at01 = ((const f32x2*)att)[2 * lane], at23 = ((const f32x2*)att)[2 * lane + 1];
    at01 *= LOG2E; at23 *= LOG2E;
    uint2 xru = *(const uint2*)(xlr + (size_t)wid * 512 + 256 + 4 * lane);
    f32x2 xr01 = b2x2(xru.x), xr23 = b2x2(xru.y);
    int s0 = start[wid], dg = deg[wid];
    const int2* ep = csr + s0;
    float m = -1e30f, d = 0.f;
    f32x2 acc01 = {0.f, 0.f}, acc23 = {0.f, 0.f};

    int2 e0 = ep[0], e1 = ep[1], e2 = ep[2], e3 = ep[3];
    uint2 r0 = *(const uint2*)(xlr + ((size_t)e0.x << 9) + 4 * lane);
    uint2 r1 = *(const uint2*)(xlr + ((size_t)e1.x << 9) + 4 * lane);
    uint2 r2 = *(const uint2*)(xlr + ((size_t)e2.x << 9) + 4 * lane);
    uint2 r3 = *(const uint2*)(xlr + ((size_t)e3.x << 9) + 4 * lane);

    for (int j = 0; j < dg; j += 4) {
        float w0 = __int_as_float(e0.y), w1 = __int_as_float(e1.y);
        float w2 = __int_as_float(e2.y), w3 = __int_as_float(e3.y);
        f32x2 a001 = b2x2(r0.x), a023 = b2x2(r0.y);
        f32x2 a101 = b2x2(r1.x), a123 = b2x2(r1.y);
        f32x2 a201 = b2x2(r2.x), a223 = b2x2(r2.y);
        f32x2 a301 = b2x2(r3.x), a323 = b2x2(r3.y);
        int jn = j + 4;
        if (jn < dg) {
            e0 = ep[jn]; e1 = ep[jn + 1]; e2 = ep[jn + 2]; e3 = ep[jn + 3];
            r0 = *(const uint2*)(xlr + ((size_t)e0.x << 9) + 4 * lane);
            r1 = *(const uint2*)(xlr + ((size_t)e1.x << 9) + 4 * lane);
            r2 = *(const uint2*)(xlr + ((size_t)e2.x << 9) + 4 * lane);
            r3 = *(const uint2*)(xlr + ((size_t)e3.x << 9) + 4 * lane);
        }
        f32x2 z, lz, ww, pv;
        ww = (f32x2){w0, w0}; pv = (f32x2){0.f, 0.f};
        z = a001 + __builtin_elementwise_fma(ww, we01, xr01);
        lz = __builtin_elementwise_max(z, z * NEG_SLOPE);
        pv = __builtin_elementwise_fma(lz, at01, pv);
        z = a023 + __builtin_elementwise_fma(ww, we23, xr23);
        lz = __builtin_elementwise_max(z, z * NEG_SLOPE);
        pv = __builtin_elementwise_fma(lz, at23, pv);
        float p0 = pv.x + pv.y;
        ww = (f32x2){w1, w1}; pv = (f32x2){0.f, 0.f};
        z = a101 + __builtin_elementwise_fma(ww, we01, xr01);
        lz = __builtin_elementwise_max(z, z * NEG_SLOPE);
        pv = __builtin_elementwise_fma(lz, at01, pv);
        z = a123 + __builtin_elementwise_fma(ww, we23, xr23);
        lz = __builtin_elementwise_max(z, z * NEG_SLOPE);
        pv = __builtin_elementwise_fma(lz, at23, pv);
        float p1 = pv.x + pv.y;
        ww = (f32x2){w2, w2}; pv = (f32x2){0.f, 0.f};
        z = a201 + __builtin_elementwise_fma(ww, we01, xr01);
        lz = __builtin_elementwise_max(z, z * NEG_SLOPE);
        pv = __builtin_elementwise_fma(lz, at01, pv);
        z = a223 + __builtin_elementwise_fma(ww, we23, xr23);
        lz = __builtin_elementwise_max(z, z * NEG_SLOPE);
        pv = __builtin_elementwise_fma(lz, at23, pv);
        float p2 = pv.x + pv.y;
        ww = (f32x2){w3, w3}; pv = (f32x2){0.f, 0.f};
        z = a301 + __builtin_elementwise_fma(ww, we01, xr01);
        lz = __builtin_elementwise_max(z, z * NEG_SLOPE);
        pv = __builtin_elementwise_fma(lz, at01, pv);
        z = a323 + __builtin_elementwise_fma(ww, we23, xr23);
        lz = __builtin_elementwise_max(z, z * NEG_SLOPE);
        pv = __builtin_elementwise_fma(lz, at23, pv);
        float p3 = pv.x + pv.y;
        p0 = dpp8_sum(p0); p1 = dpp8_sum(p1);
        p2 = dpp8_sum(p2); p3 = dpp8_sum(p3);
        if (j + 1 >= dg) p1 = -1e30f;
        if (j + 2 >= dg) p2 = -1e30f;
        if (j + 3 >= dg) p3 = -1e30f;
        float pm = fmaxf(fmaxf(p0, p1), fmaxf(p2, p3));
        if (__any(pm > m + RESCALE_THR2)) {
            float nm = fmaxf(m, pm);
            float sc = EXP2(m - nm);
            d *= sc;
            acc01 *= sc; acc23 *= sc;
            m = nm;
        }
        float q0 = EXP2(p0 - m), q1 = EXP2(p1 - m);
        float q2 = EXP2(p2 - m), q3 = EXP2(p3 - m);
        d += (q0 + q1) + (q2 + q3);
        f32x2 qq;
        qq = (f32x2){q0, q0};
        acc01 = __builtin_elementwise_fma(qq, a001, acc01);
        acc23 = __builtin_elementwise_fma(qq, a023, acc23);
        qq = (f32x2){q1, q1};
        acc01 = __builtin_elementwise_fma(qq, a101, acc01);
        acc23 = __builtin_elementwise_fma(qq, a123, acc23);
        qq = (f32x2){q2, q2};
        acc01 = __builtin_elementwise_fma(qq, a201, acc01);
        acc23 = __builtin_elementwise_fma(qq, a223, acc23);
        qq = (f32x2){q3, q3};
        acc01 = __builtin_elementwise_fma(qq, a301, acc01);
        acc23 = __builtin_elementwise_fma(qq, a323, acc23);
    }
    float inv = 1.f / (d + 1e-16f);
    f32x2 b01 = ((const f32x2*)b1)[2 * lane], b23 = ((const f32x2*)b1)[2 * lane + 1];
    ushort4 o;
    o.x = f2b(fmaxf(fmaf(acc01.x, inv, b01.x), 0.f));
    o.y = f2b(fmaxf(fmaf(acc01.y, inv, b01.y), 0.f));
    o.z = f2b(fmaxf(fmaf(acc23.x, inv, b23.x), 0.f));
    o.w = f2b(fmaxf(fmaf(acc23.y, inv, b23.y), 0.f));
    *(ushort4*)(out1 + (size_t)wid * 256 + 4 * lane) = o;
}

// ---- fused layer-2 + pool: 16 threads/node = 2 edge-slots x 8 channels ----
// slot s handles edge pairs {4t+2s, 4t+2s+1}; 1-step logsumexp merge at end.
__global__ __launch_bounds__(256) void k_gat2(
    const unsigned short* __restrict__ xlr2,
    const int* __restrict__ start, const int* __restrict__ deg,
    const int2* __restrict__ csr,
    const float* __restrict__ We, const float* __restrict__ att,
    const float* __restrict__ b2, const int* __restrict__ batch,
    float* __restrict__ pool, float* __restrict__ cnt)
{
    int gt = blockIdx.x * blockDim.x + threadIdx.x;
    int i = gt >> 4;                 // node
    int sub = gt & 15;
    int s = sub >> 3;                // edge slot 0..1
    int g = sub & 7;                 // channel group 0..7
    if (i >= N_NODES) return;
    f32x2 we01 = ((const f32x2*)We)[2 * g],  we23 = ((const f32x2*)We)[2 * g + 1];
    f32x2 at01 = ((const f32x2*)att)[2 * g], at23 = ((const f32x2*)att)[2 * g + 1];
    at01 *= LOG2E; at23 *= LOG2E;
    uint2 xru = *(const uint2*)(xlr2 + (size_t)i * 64 + 32 + 4 * g);
    f32x2 xr01 = b2x2(xru.x), xr23 = b2x2(xru.y);
    int s0 = start[i], dg = deg[i];
    const int2* ep = csr + s0;
    float m = -1e30f, d = 0.f;
    f32x2 acc01 = {0.f, 0.f}, acc23 = {0.f, 0.f};

    int T = (dg + 3) >> 2;
    int2 ec0 = ep[2 * s], ec1 = ep[2 * s + 1];
    uint2 ra0 = *(const uint2*)(xlr2 + ((size_t)ec0.x << 6) + 4 * g);
    uint2 ra1 = *(const uint2*)(xlr2 + ((size_t)ec1.x << 6) + 4 * g);

    for (int t = 0; t < T; ++t) {
        int j0 = 4 * t + 2 * s;
        int2 c0 = ec0, c1 = ec1;
        uint2 A0 = ra0, A1 = ra1;
        if (t + 1 < T) {
            int jn = 4 * (t + 1) + 2 * s;
            ec0 = ep[jn]; ec1 = ep[jn + 1];
            ra0 = *(const uint2*)(xlr2 + ((size_t)ec0.x << 6) + 4 * g);
            ra1 = *(const uint2*)(xlr2 + ((size_t)ec1.x << 6) + 4 * g);
        }
        float w0 = __int_as_float(c0.y), w1 = __int_as_float(c1.y);
        f32x2 ww0 = {w0, w0}, ww1 = {w1, w1};
        f32x2 a001 = b2x2(A0.x), a023 = b2x2(A0.y);
        f32x2 a101 = b2x2(A1.x), a123 = b2x2(A1.y);
        f32x2 p0v = {0.f, 0.f}, p1v = {0.f, 0.f}, z, lz;
        z = a001 + __builtin_elementwise_fma(ww0, we01, xr01);
        lz = __builtin_elementwise_max(z, z * NEG_SLOPE);
        p0v = __builtin_elementwise_fma(lz, at01, p0v);
        z = a023 + __builtin_elementwise_fma(ww0, we23, xr23);
        lz = __builtin_elementwise_max(z, z * NEG_SLOPE);
        p0v = __builtin_elementwise_fma(lz, at23, p0v);
        z = a101 + __builtin_elementwise_fma(ww1, we01, xr01);
        lz = __builtin_elementwise_max(z, z * NEG_SLOPE);
        p1v = __builtin_elementwise_fma(lz, at01, p1v);
        z = a123 + __builtin_elementwise_fma(ww1, we23, xr23);
        lz = __builtin_elementwise_max(z, z * NEG_SLOPE);
        p1v = __builtin_elementwise_fma(lz, at23, p1v);
        float p0 = dpp8_sum(p0v.x + p0v.y);
        float p1 = dpp8_sum(p1v.x + p1v.y);
        bool v0 = j0 < dg, v1 = j0 + 1 < dg;
        if (!v0) p0 = -1e30f;
        if (!v1) p1 = -1e30f;
        float pm = fmaxf(p0, p1);
        if (__any(pm > m + RESCALE_THR2)) {
            float nm = fmaxf(m, pm);
            float sc = EXP2(m - nm);
            d *= sc;
            acc01 *= sc; acc23 *= sc;
            m = nm;
        }
        float q0 = v0 ? EXP2(p0 - m) : 0.f;
        float q1 = v1 ? EXP2(p1 - m) : 0.f;
        d += q0 + q1;
        f32x2 qq0 = {q0, q0}, qq1 = {q1, q1};
        acc01 = __builtin_elementwise_fma(qq0, a001, acc01);
        acc23 = __builtin_elementwise_fma(qq0, a023, acc23);
        acc01 = __builtin_elementwise_fma(qq1, a101, acc01);
        acc23 = __builtin_elementwise_fma(qq1, a123, acc23);
    }

    // merge the 2 slots (lanes differing in bit 3): exact logsumexp merge
    {
        float mo = __shfl_xor(m, 8);
        float dd = __shfl_xor(d, 8);
        f32x2 ao01, ao23;
        ao01.x = __shfl_xor(acc01.x, 8); ao01.y = __shfl_xor(acc01.y, 8);
        ao23.x = __shfl_xor(acc23.x, 8); ao23.y = __shfl_xor(acc23.y, 8);
        float nm = fmaxf(m, mo);
        float sa = EXP2(m - nm), sb = EXP2(mo - nm);
        d = d * sa + dd * sb;
        f32x2 va = {sa, sa}, vb = {sb, sb};
        acc01 = acc01 * va + ao01 * vb;
        acc23 = acc23 * va + ao23 * vb;
    }

    if (s == 0) {
        float inv = 1.f / (d + 1e-16f);
        f32x2 b01 = ((const f32x2*)b2)[2 * g], b23 = ((const f32x2*)b2)[2 * g + 1];
        float vx = fmaxf(fmaf(acc01.x, inv, b01.x), 0.f);
        float vy = fmaxf(fmaf(acc01.y, inv, b01.y), 0.f);
        float vz = fmaxf(fmaf(acc23.x, inv, b23.x), 0.f);
        float vw = fmaxf(fmaf(acc23.y, inv, b23.y), 0.f);
        int b = batch[i];
        float* o = pool + (size_t)b * D_H + g * 4;
        atomicAdd(o + 0, vx);
        atomicAdd(o + 1, vy);
        atomicAdd(o + 2, vz);
        atomicAdd(o + 3, vw);
        if (g == 0) atomicAdd(&cnt[b], 1.0f);
    }
}

// ---- mean, sigmoid, final FC ----
__global__ void k_final(const float* __restrict__ pool, const float* __restrict__ cnt,
                        const float* __restrict__ Wfc, const float* __restrict__ bfc,
                        float* __restrict__ out)
{
    int b = blockIdx.x * blockDim.x + threadIdx.x;
    if (b >= N_GRAPHS) return;
    float c = cnt[b]; c = c > 1.f ? c : 1.f;
    float acc = 0.f;
    #pragma unroll
    for (int j = 0; j < D_H; ++j) {
        float f = pool[b * D_H + j] / c;
        f = 1.f / (1.f + __expf(-f));
        acc = fmaf(f, Wfc[j], acc);
    }
    out[b] = acc + bfc[0];
}

extern "C" void kernel_launch(void* const* d_in, const int* in_sizes, int n_in,
                              void* d_out, int out_size, void* d_ws, size_t ws_size,
                              hipStream_t stream)
{
    const float* x    = (const float*)d_in[0];
    const int*   ei   = (const int*)  d_in[1];
    const int*   batch= (const int*)  d_in[2];
    const float* ew   = (const float*)d_in[3];
    const float* Wl1  = (const float*)d_in[4];
    const float* Wr1  = (const float*)d_in[5];
    const float* We1  = (const float*)d_in[6];
    const float* att1 = (const float*)d_in[7];
    const float* b1   = (const float*)d_in[8];
    const float* Wl2  = (const float*)d_in[9];
    const float* Wr2  = (const float*)d_in[10];
    const float* We2  = (const float*)d_in[11];
    const float* att2 = (const float*)d_in[12];
    const float* b2   = (const float*)d_in[13];
    const float* Wfc  = (const float*)d_in[14];
    const float* bfc  = (const float*)d_in[15];
    float* out = (float*)d_out;

    float* ws = (float*)d_ws;
    size_t off = 0;
    auto take = [&](size_t n) -> float* {
        float* p = ws + off;
        off = (off + n + 63) & ~(size_t)63;
        return p;
    };
    // --- zero-initialized region ---
    float* fillsum = take(1);
    int*   deg  = (int*)take(N_NODES);
    float* cnt  = take(N_GRAPHS);
    float* pool = take((size_t)N_GRAPHS * D_H);
    size_t zero_elems = off;
    // --- written-before-read buffers ---
    int*   start = (int*)take(N_NODES);
    int*   rank  = (int*)take(E_TOT);
    int*   bsum  = (int*)take(256);
    int2*  csr   = (int2*)take((size_t)(E_TOT + 8) * 2);
    unsigned short* Wt1  = (unsigned short*)take(512 * 128 / 2);
    unsigned short* Wt2  = (unsigned short*)take(64 * 256 / 2);
    unsigned short* xlr1 = (unsigned short*)take((size_t)N_NODES * 512 / 2);
    unsigned short* out1 = (unsigned short*)take((size_t)N_NODES * 256 / 2);
    unsigned short* xlr2 = (unsigned short*)take((size_t)N_NODES * 64 / 2);
    (void)ws_size; (void)in_sizes; (void)n_in; (void)out_size;

    hipMemsetAsync(d_ws, 0, zero_elems * sizeof(float), stream);

    // front: fill-value sum + degree histogram (captures rank) + weight panels
    k_front<<<RS_BLK + HIST_BLK + W1_BLK + W2_BLK, 256, 0, stream>>>(
        ew, ei, Wl1, Wr1, Wl2, Wr2, fillsum, deg, rank, Wt1, Wt2);

    // 3-kernel scan (scan3 writes csr slack entries)
    k_scan1<<<NSCAN_BLK, 256, 0, stream>>>(deg, start, bsum);
    k_scan2<<<1, 256, 0, stream>>>(bsum, NSCAN_BLK);
    k_scan3<<<NSCAN_BLK, 256, 0, stream>>>(start, bsum, csr);

    // hybrid: layer-1 projection (fused cast) || atomic-free CSR scatter
    k_gemm1_scatter<<<HY_TOT, 256, 0, stream>>>(
        x, Wt1, xlr1, ei, ew, fillsum, start, rank, csr);

    // fused layer-1 edge phase
    k_gat1<<<(N_NODES * 64 + 255) / 256, 256, 0, stream>>>(
        xlr1, start, deg, csr, We1, att1, b1, out1);

    // layer-2 projection: xlr2 = out1 @ [Wl2|Wr2]
    k_gemm2<<<dim3(1, (N_NODES + 63) / 64), 256, 0, stream>>>(
        out1, Wt2, xlr2, N_NODES);

    // fused layer-2 edge phase + pooling (16 threads per node)
    k_gat2<<<((size_t)N_NODES * 16 + 255) / 256, 256, 0, stream>>>(
        xlr2, start, deg, csr, We2, att2, b2, batch, pool, cnt);

    // final FC
    k_final<<<(N_GRAPHS + 255) / 256, 256, 0, stream>>>(pool, cnt, Wfc, bfc, out);
}

// Round 16
// 269.276 us; speedup vs baseline: 1.0477x; 1.0477x over previous
//
#include <hip/hip_runtime.h>
#include <math.h>

#define N_NODES 50000
#define N_EDGES 800000
#define D_IN    128
#define D_H     32
#define N_HEADS 8
#define N_GRAPHS 512
#define E_TOT   (N_EDGES + N_NODES)      // 850000 (with self-loops)
#define HDIM    (N_HEADS * D_H)          // 256
#define NEG_SLOPE 0.2f
#define NSCAN_BLK ((N_NODES + 255) / 256)   // 196
#define LOG2E 1.4426950408889634f
#define RESCALE_THR2 11.0f               // ~8 nats in log2 units

typedef short bfrag8 __attribute__((ext_vector_type(8)));   // 8 bf16 = 4 VGPRs
typedef float f32x4 __attribute__((ext_vector_type(4)));
typedef float f32x2 __attribute__((ext_vector_type(2)));

#if __has_builtin(__builtin_amdgcn_exp2f)
#define EXP2(x) __builtin_amdgcn_exp2f(x)
#else
#define EXP2(x) exp2f(x)
#endif

// ---- bf16 helpers ----
__device__ __forceinline__ unsigned short f2b(float x) {
    unsigned u = __float_as_uint(x);
    unsigned r = u + 0x7FFFu + ((u >> 16) & 1u);   // round-to-nearest-even
    return (unsigned short)(r >> 16);
}
__device__ __forceinline__ f32x2 b2x2(unsigned u) {
    f32x2 v;
    v.x = __uint_as_float(u << 16);
    v.y = __uint_as_float(u & 0xFFFF0000u);
    return v;
}

// ---- 8-lane sum via DPP (VALU-only; no LDS pipe / lgkmcnt) ----
__device__ __forceinline__ float dpp8_sum(float x) {
    x += __int_as_float(__builtin_amdgcn_mov_dpp(__float_as_int(x), 0xB1, 0xF, 0xF, true));
    x += __int_as_float(__builtin_amdgcn_mov_dpp(__float_as_int(x), 0x4E, 0xF, 0xF, true));
    x += __int_as_float(__builtin_amdgcn_mov_dpp(__float_as_int(x), 0x141, 0xF, 0xF, true));
    return x;
}

// ==== fused front kernel: reduce_sum | hist(+rank) | weight panels ====
#define RS_BLK   512
#define HIST_BLK ((E_TOT + 255) / 256)       // 3321
#define W1_BLK   (512 * 128 / 256)           // 256
#define W2_BLK   (64 * 256 / 256)            // 64
__global__ void k_front(const float* __restrict__ ew, const int* __restrict__ ei,
                        const float* __restrict__ Wl1, const float* __restrict__ Wr1,
                        const float* __restrict__ Wl2, const float* __restrict__ Wr2,
                        float* __restrict__ fillsum, int* __restrict__ deg,
                        int* __restrict__ rank,
                        unsigned short* __restrict__ Wt1,
                        unsigned short* __restrict__ Wt2) {
    __shared__ float ls[4];
    int b = blockIdx.x;
    if (b < RS_BLK) {
        int t = b * 256 + threadIdx.x;
        float s = 0.f;
        for (int i = t; i < N_EDGES; i += RS_BLK * 256) s += ew[i];
        for (int m = 1; m < 64; m <<= 1) s += __shfl_xor(s, m);
        int lane = threadIdx.x & 63, wv = threadIdx.x >> 6;
        if (lane == 0) ls[wv] = s;
        __syncthreads();
        if (threadIdx.x == 0) atomicAdd(fillsum, ls[0] + ls[1] + ls[2] + ls[3]);
    } else if (b < RS_BLK + HIST_BLK) {
        int e = (b - RS_BLK) * 256 + threadIdx.x;
        if (e >= E_TOT) return;
        int dst = (e < N_EDGES) ? ei[N_EDGES + e] : (e - N_EDGES);
        rank[e] = atomicAdd(&deg[dst], 1);   // rank is free: atomic returns old
    } else if (b < RS_BLK + HIST_BLK + W1_BLK) {
        int t = (b - RS_BLK - HIST_BLK) * 256 + threadIdx.x;   // t = c*128 + k
        int c = t >> 7, k = t & 127;
        float v = (c < 256) ? Wl1[k * 256 + c] : Wr1[k * 256 + (c - 256)];
        Wt1[t] = f2b(v);
    } else {
        int t = (b - RS_BLK - HIST_BLK - W1_BLK) * 256 + threadIdx.x;   // t = c*256 + k
        int c = t >> 8, k = t & 255;
        float v = (c < 32) ? Wl2[k * 32 + c] : Wr2[k * 32 + (c - 32)];
        Wt2[t] = f2b(v);
    }
}

// ---- CSR scan (exclusive), 3-kernel version ----
__global__ void k_scan1(const int* __restrict__ deg, int* __restrict__ start,
                        int* __restrict__ bsum) {
    __shared__ int sh[256];
    int i = blockIdx.x * 256 + threadIdx.x;
    int v = (i < N_NODES) ? deg[i] : 0;
    sh[threadIdx.x] = v;
    __syncthreads();
    for (int o = 1; o < 256; o <<= 1) {
        int t = (threadIdx.x >= o) ? sh[threadIdx.x - o] : 0;
        __syncthreads();
        sh[threadIdx.x] += t;
        __syncthreads();
    }
    if (i < N_NODES) start[i] = sh[threadIdx.x] - v;
    if (threadIdx.x == 255) bsum[blockIdx.x] = sh[255];
}
__global__ void k_scan2(int* __restrict__ bsum, int nb) {
    __shared__ int sh[256];
    int v = (threadIdx.x < nb) ? bsum[threadIdx.x] : 0;
    sh[threadIdx.x] = v;
    __syncthreads();
    for (int o = 1; o < 256; o <<= 1) {
        int t = (threadIdx.x >= o) ? sh[threadIdx.x - o] : 0;
        __syncthreads();
        sh[threadIdx.x] += t;
        __syncthreads();
    }
    if (threadIdx.x < nb) bsum[threadIdx.x] = sh[threadIdx.x] - v;
}
// finalizes start[] and writes csr slack entries for unguarded prefetch
__global__ void k_scan3(int* __restrict__ start, const int* __restrict__ bsum,
                        int2* __restrict__ csr) {
    int i = blockIdx.x * 256 + threadIdx.x;
    if (i < N_NODES) start[i] += bsum[blockIdx.x];
    if (i == 0) {
        #pragma unroll
        for (int k = 0; k < 8; ++k) csr[E_TOT + k] = make_int2(0, 0);
    }
}

// ==== hybrid: GEMM1 (128x128 tile, fused f32->bf16 cast) || atomic-free scatter ====
#define G1_BLOCKS 1564                       // 4 cols x 391 row-blocks
#define SC_BLOCKS ((E_TOT + 255) / 256)      // 3321
#define HY_TOT    4985
__global__ __launch_bounds__(256) void k_gemm1_scatter(
    const float* __restrict__ A, const unsigned short* __restrict__ Bt,
    unsigned short* __restrict__ C,
    const int* __restrict__ ei, const float* __restrict__ ew,
    const float* __restrict__ fillsum, const int* __restrict__ start,
    const int* __restrict__ rank, int2* __restrict__ csr)
{
    const int KC = 128, NN = 512, M = N_NODES;
    __shared__ unsigned short A_lds[128][KC + 8];
    __shared__ unsigned short B_lds[128][KC + 8];
    int bid = blockIdx.x;
    int tid = threadIdx.x;
    if (bid % 3 != 0) {
        // ---- scatter part: pos from precomputed rank, NO atomics ----
        int sid = bid - bid / 3 - 1;
        if (sid >= SC_BLOCKS) return;
        int e = sid * 256 + tid;
        if (e >= E_TOT) return;
        int src, dst; float w;
        if (e < N_EDGES) { src = ei[e]; dst = ei[N_EDGES + e]; w = ew[e]; }
        else { src = dst = e - N_EDGES; w = fillsum[0] * (1.0f / N_EDGES); }
        int pos = start[dst] + rank[e];
        csr[pos] = make_int2(src, __float_as_int(w));
        return;
    }
    int gid = bid / 3;
    if (gid >= G1_BLOCKS) return;
    int row0 = (gid >> 2) * 128, col0 = (gid & 3) * 128;
    for (int idx = tid; idx < 128 * 32; idx += 256) {
        int r = idx >> 5, c4 = idx & 31;
        int gr = row0 + r;
        float4 v = {0.f, 0.f, 0.f, 0.f};
        if (gr < M) v = ((const float4*)(A + (size_t)gr * KC))[c4];
        ushort4 o;
        o.x = f2b(v.x); o.y = f2b(v.y); o.z = f2b(v.z); o.w = f2b(v.w);
        *(ushort4*)&A_lds[r][c4 * 4] = o;
    }
    for (int idx = tid; idx < 128 * 16; idx += 256) {
        int r = idx >> 4, ch = idx & 15;
        uint4 v = *(const uint4*)(Bt + (size_t)(col0 + r) * KC + ch * 8);
        *(uint4*)&B_lds[r][ch * 8] = v;
    }
    __syncthreads();

    int wid = tid >> 6, lane = tid & 63;
    int wy = wid >> 1, wx = wid & 1;
    int lr = lane & 15, lh = lane >> 4;
    f32x4 acc[4][4] = {};
    #pragma unroll
    for (int k0 = 0; k0 < KC; k0 += 32) {
        bfrag8 af[4], bf[4];
        #pragma unroll
        for (int i = 0; i < 4; ++i) {
            af[i] = *(const bfrag8*)&A_lds[64 * wy + 16 * i + lr][k0 + lh * 8];
            bf[i] = *(const bfrag8*)&B_lds[64 * wx + 16 * i + lr][k0 + lh * 8];
        }
        #pragma unroll
        for (int mi = 0; mi < 4; ++mi)
            #pragma unroll
            for (int ni = 0; ni < 4; ++ni)
                acc[mi][ni] = __builtin_amdgcn_mfma_f32_16x16x32_bf16(af[mi], bf[ni], acc[mi][ni], 0, 0, 0);
    }
    #pragma unroll
    for (int mi = 0; mi < 4; ++mi) {
        #pragma unroll
        for (int ni = 0; ni < 4; ++ni) {
            #pragma unroll
            for (int r = 0; r < 4; ++r) {
                int row = row0 + 64 * wy + 16 * mi + lh * 4 + r;
                if (row < M)
                    C[(size_t)row * NN + col0 + 64 * wx + 16 * ni + lr] = f2b(acc[mi][ni][r]);
            }
        }
    }
}

// ---- GEMM2: 64x64 tile, bf16 MFMA: C[M,64] = A[M,256] * Bt[64,256]^T ----
__global__ __launch_bounds__(256) void k_gemm2(
    const unsigned short* __restrict__ A, const unsigned short* __restrict__ Bt,
    unsigned short* __restrict__ C, int M)
{
    const int KC = 256, NN = 64;
    __shared__ unsigned short A_lds[64][KC + 8];
    __shared__ unsigned short B_lds[64][KC + 8];
    int row0 = blockIdx.y * 64, col0 = 0;
    int tid = threadIdx.x;
    const int CPR = KC / 8;
    for (int idx = tid; idx < 64 * CPR; idx += 256) {
        int r = idx / CPR, ch = idx % CPR;
        int gr = row0 + r;
        uint4 v = {0u, 0u, 0u, 0u};
        if (gr < M) v = *(const uint4*)(A + (size_t)gr * KC + ch * 8);
        *(uint4*)&A_lds[r][ch * 8] = v;
    }
    for (int idx = tid; idx < 64 * CPR; idx += 256) {
        int r = idx / CPR, ch = idx % CPR;
        uint4 v = *(const uint4*)(Bt + (size_t)(col0 + r) * KC + ch * 8);
        *(uint4*)&B_lds[r][ch * 8] = v;
    }
    __syncthreads();

    int wid = tid >> 6, lane = tid & 63;
    int wy = wid >> 1, wx = wid & 1;
    int lr = lane & 15, lh = lane >> 4;
    f32x4 acc[2][2] = {};
    #pragma unroll
    for (int k0 = 0; k0 < KC; k0 += 32) {
        bfrag8 a0 = *(const bfrag8*)&A_lds[32 * wy + lr][k0 + lh * 8];
        bfrag8 a1 = *(const bfrag8*)&A_lds[32 * wy + 16 + lr][k0 + lh * 8];
        bfrag8 b0 = *(const bfrag8*)&B_lds[32 * wx + lr][k0 + lh * 8];
        bfrag8 b1 = *(const bfrag8*)&B_lds[32 * wx + 16 + lr][k0 + lh * 8];
        acc[0][0] = __builtin_amdgcn_mfma_f32_16x16x32_bf16(a0, b0, acc[0][0], 0, 0, 0);
        acc[0][1] = __builtin_amdgcn_mfma_f32_16x16x32_bf16(a0, b1, acc[0][1], 0, 0, 0);
        acc[1][0] = __builtin_amdgcn_mfma_f32_16x16x32_bf16(a1, b0, acc[1][0], 0, 0, 0);
        acc[1][1] = __builtin_amdgcn_mfma_f32_16x16x32_bf16(a1, b1, acc[1][1], 0, 0, 0);
    }
    #pragma unroll
    for (int mt = 0; mt < 2; ++mt) {
        #pragma unroll
        for (int nt = 0; nt < 2; ++nt) {
            #pragma unroll
            for (int r = 0; r < 4; ++r) {
                int row = row0 + 32 * wy + 16 * mt + lh * 4 + r;
                if (row < M)
                    C[(size_t)row * NN + col0 + 32 * wx + 16 * nt + lr] = f2b(acc[mt][nt][r]);
            }
        }
    }
}

// ---- fused layer-1: one wave per node; lane owns 4 of 256 channels ----
// 4-edge unroll, unguarded prefetch (slack entries), DPP reduce, log2 softmax.
__global__ __launch_bounds__(256) void k_gat1(
    const unsigned short* __restrict__ xlr,
    const int* __restrict__ start, const int* __restrict__ deg,
    const int2* __restrict__ csr,
    const float* __restrict__ We, const float* __restrict__ att,
    const float* __restrict__ b1, unsigned short* __restrict__ out1)
{
    int wid = (blockIdx.x * blockDim.x + threadIdx.x) >> 6;
    int lane = threadIdx.x & 63;
    if (wid >= N_NODES) return;
    f32x2 we01 = ((const f32x2*)We)[2 * lane],  we23 = ((const f32x2*)We)[2 * lane + 1];
    f32x2 at01 = ((const f32x2*)att)[2 * lane], at23 = ((const f32x2*)att)[2 * lane + 1];
    at01 *= LOG2E; at23 *= LOG2E;
    uint2 xru = *(const uint2*)(xlr + (size_t)wid * 512 + 256 + 4 * lane);
    f32x2 xr01 = b2x2(xru.x), xr23 = b2x2(xru.y);
    int s0 = start[wid], dg = deg[wid];
    const int2* ep = csr + s0;
    float m = -1e30f, d = 0.f;
    f32x2 acc01 = {0.f, 0.f}, acc23 = {0.f, 0.f};

    int2 e0 = ep[0], e1 = ep[1], e2 = ep[2], e3 = ep[3];
    uint2 r0 = *(const uint2*)(xlr + ((size_t)e0.x << 9) + 4 * lane);
    uint2 r1 = *(const uint2*)(xlr + ((size_t)e1.x << 9) + 4 * lane);
    uint2 r2 = *(const uint2*)(xlr + ((size_t)e2.x << 9) + 4 * lane);
    uint2 r3 = *(const uint2*)(xlr + ((size_t)e3.x << 9) + 4 * lane);

    for (int j = 0; j < dg; j += 4) {
        float w0 = __int_as_float(e0.y), w1 = __int_as_float(e1.y);
        float w2 = __int_as_float(e2.y), w3 = __int_as_float(e3.y);
        f32x2 a001 = b2x2(r0.x), a023 = b2x2(r0.y);
        f32x2 a101 = b2x2(r1.x), a123 = b2x2(r1.y);
        f32x2 a201 = b2x2(r2.x), a223 = b2x2(r2.y);
        f32x2 a301 = b2x2(r3.x), a323 = b2x2(r3.y);
        int jn = j + 4;
        if (jn < dg) {
            e0 = ep[jn]; e1 = ep[jn + 1]; e2 = ep[jn + 2]; e3 = ep[jn + 3];
            r0 = *(const uint2*)(xlr + ((size_t)e0.x << 9) + 4 * lane);
            r1 = *(const uint2*)(xlr + ((size_t)e1.x << 9) + 4 * lane);
            r2 = *(const uint2*)(xlr + ((size_t)e2.x << 9) + 4 * lane);
            r3 = *(const uint2*)(xlr + ((size_t)e3.x << 9) + 4 * lane);
        }
        f32x2 z, lz, ww, pv;
        ww = (f32x2){w0, w0}; pv = (f32x2){0.f, 0.f};
        z = a001 + __builtin_elementwise_fma(ww, we01, xr01);
        lz = __builtin_elementwise_max(z, z * NEG_SLOPE);
        pv = __builtin_elementwise_fma(lz, at01, pv);
        z = a023 + __builtin_elementwise_fma(ww, we23, xr23);
        lz = __builtin_elementwise_max(z, z * NEG_SLOPE);
        pv = __builtin_elementwise_fma(lz, at23, pv);
        float p0 = pv.x + pv.y;
        ww = (f32x2){w1, w1}; pv = (f32x2){0.f, 0.f};
        z = a101 + __builtin_elementwise_fma(ww, we01, xr01);
        lz = __builtin_elementwise_max(z, z * NEG_SLOPE);
        pv = __builtin_elementwise_fma(lz, at01, pv);
        z = a123 + __builtin_elementwise_fma(ww, we23, xr23);
        lz = __builtin_elementwise_max(z, z * NEG_SLOPE);
        pv = __builtin_elementwise_fma(lz, at23, pv);
        float p1 = pv.x + pv.y;
        ww = (f32x2){w2, w2}; pv = (f32x2){0.f, 0.f};
        z = a201 + __builtin_elementwise_fma(ww, we01, xr01);
        lz = __builtin_elementwise_max(z, z * NEG_SLOPE);
        pv = __builtin_elementwise_fma(lz, at01, pv);
        z = a223 + __builtin_elementwise_fma(ww, we23, xr23);
        lz = __builtin_elementwise_max(z, z * NEG_SLOPE);
        pv = __builtin_elementwise_fma(lz, at23, pv);
        float p2 = pv.x + pv.y;
        ww = (f32x2){w3, w3}; pv = (f32x2){0.f, 0.f};
        z = a301 + __builtin_elementwise_fma(ww, we01, xr01);
        lz = __builtin_elementwise_max(z, z * NEG_SLOPE);
        pv = __builtin_elementwise_fma(lz, at01, pv);
        z = a323 + __builtin_elementwise_fma(ww, we23, xr23);
        lz = __builtin_elementwise_max(z, z * NEG_SLOPE);
        pv = __builtin_elementwise_fma(lz, at23, pv);
        float p3 = pv.x + pv.y;
        p0 = dpp8_sum(p0); p1 = dpp8_sum(p1);
        p2 = dpp8_sum(p2); p3 = dpp8_sum(p3);
        if (j + 1 >= dg) p1 = -1e30f;
        if (j + 2 >= dg) p2 = -1e30f;
        if (j + 3 >= dg) p3 = -1e30f;
        float pm = fmaxf(fmaxf(p0, p1), fmaxf(p2, p3));
        if (__any(pm > m + RESCALE_THR2)) {
            float nm = fmaxf(m, pm);
            float sc = EXP2(m - nm);
            d *= sc;
            acc01 *= sc; acc23 *= sc;
            m = nm;
        }
        float q0 = EXP2(p0 - m), q1 = EXP2(p1 - m);
        float q2 = EXP2(p2 - m), q3 = EXP2(p3 - m);
        d += (q0 + q1) + (q2 + q3);
        f32x2 qq;
        qq = (f32x2){q0, q0};
        acc01 = __builtin_elementwise_fma(qq, a001, acc01);
        acc23 = __builtin_elementwise_fma(qq, a023, acc23);
        qq = (f32x2){q1, q1};
        acc01 = __builtin_elementwise_fma(qq, a101, acc01);
        acc23 = __builtin_elementwise_fma(qq, a123, acc23);
        qq = (f32x2){q2, q2};
        acc01 = __builtin_elementwise_fma(qq, a201, acc01);
        acc23 = __builtin_elementwise_fma(qq, a223, acc23);
        qq = (f32x2){q3, q3};
        acc01 = __builtin_elementwise_fma(qq, a301, acc01);
        acc23 = __builtin_elementwise_fma(qq, a323, acc23);
    }
    float inv = 1.f / (d + 1e-16f);
    f32x2 b01 = ((const f32x2*)b1)[2 * lane], b23 = ((const f32x2*)b1)[2 * lane + 1];
    ushort4 o;
    o.x = f2b(fmaxf(fmaf(acc01.x, inv, b01.x), 0.f));
    o.y = f2b(fmaxf(fmaf(acc01.y, inv, b01.y), 0.f));
    o.z = f2b(fmaxf(fmaf(acc23.x, inv, b23.x), 0.f));
    o.w = f2b(fmaxf(fmaf(acc23.y, inv, b23.y), 0.f));
    *(ushort4*)(out1 + (size_t)wid * 256 + 4 * lane) = o;
}

// ---- fused layer-2 + pool: 8 threads per node (r14 structure, 2-edge unroll) ----
__global__ __launch_bounds__(256) void k_gat2(
    const unsigned short* __restrict__ xlr2,
    const int* __restrict__ start, const int* __restrict__ deg,
    const int2* __restrict__ csr,
    const float* __restrict__ We, const float* __restrict__ att,
    const float* __restrict__ b2, const int* __restrict__ batch,
    float* __restrict__ pool, float* __restrict__ cnt)
{
    int gt = blockIdx.x * blockDim.x + threadIdx.x;
    int i = gt >> 3, g = gt & 7;
    if (i >= N_NODES) return;
    f32x2 we01 = ((const f32x2*)We)[2 * g],  we23 = ((const f32x2*)We)[2 * g + 1];
    f32x2 at01 = ((const f32x2*)att)[2 * g], at23 = ((const f32x2*)att)[2 * g + 1];
    at01 *= LOG2E; at23 *= LOG2E;
    uint2 xru = *(const uint2*)(xlr2 + (size_t)i * 64 + 32 + 4 * g);
    f32x2 xr01 = b2x2(xru.x), xr23 = b2x2(xru.y);
    int s0 = start[i], dg = deg[i];
    const int2* ep = csr + s0;
    float m = -1e30f, d = 0.f;
    f32x2 acc01 = {0.f, 0.f}, acc23 = {0.f, 0.f};

    int2 ec0 = ep[0], ec1 = ep[1];
    uint2 ra0 = *(const uint2*)(xlr2 + ((size_t)ec0.x << 6) + 4 * g);
    uint2 ra1 = *(const uint2*)(xlr2 + ((size_t)ec1.x << 6) + 4 * g);

    for (int j = 0; j < dg; j += 2) {
        int2 c0 = ec0, c1 = ec1;
        uint2 A0 = ra0, A1 = ra1;
        int jn = j + 2;
        if (jn < dg) {
            ec0 = ep[jn]; ec1 = ep[jn + 1];
            ra0 = *(const uint2*)(xlr2 + ((size_t)ec0.x << 6) + 4 * g);
            ra1 = *(const uint2*)(xlr2 + ((size_t)ec1.x << 6) + 4 * g);
        }
        float w0 = __int_as_float(c0.y), w1 = __int_as_float(c1.y);
        f32x2 ww0 = {w0, w0}, ww1 = {w1, w1};
        f32x2 a001 = b2x2(A0.x), a023 = b2x2(A0.y);
        f32x2 a101 = b2x2(A1.x), a123 = b2x2(A1.y);
        f32x2 p0v = {0.f, 0.f}, p1v = {0.f, 0.f}, z, lz;
        z = a001 + __builtin_elementwise_fma(ww0, we01, xr01);
        lz = __builtin_elementwise_max(z, z * NEG_SLOPE);
        p0v = __builtin_elementwise_fma(lz, at01, p0v);
        z = a023 + __builtin_elementwise_fma(ww0, we23, xr23);
        lz = __builtin_elementwise_max(z, z * NEG_SLOPE);
        p0v = __builtin_elementwise_fma(lz, at23, p0v);
        z = a101 + __builtin_elementwise_fma(ww1, we01, xr01);
        lz = __builtin_elementwise_max(z, z * NEG_SLOPE);
        p1v = __builtin_elementwise_fma(lz, at01, p1v);
        z = a123 + __builtin_elementwise_fma(ww1, we23, xr23);
        lz = __builtin_elementwise_max(z, z * NEG_SLOPE);
        p1v = __builtin_elementwise_fma(lz, at23, p1v);
        float p0 = dpp8_sum(p0v.x + p0v.y);
        float p1 = dpp8_sum(p1v.x + p1v.y);
        if (j + 1 >= dg) p1 = -1e30f;
        float pm = fmaxf(p0, p1);
        if (__any(pm > m + RESCALE_THR2)) {
            float nm = fmaxf(m, pm);
            float sc = EXP2(m - nm);
            d *= sc;
            acc01 *= sc; acc23 *= sc;
            m = nm;
        }
        float q0 = EXP2(p0 - m), q1 = EXP2(p1 - m);
        d += q0 + q1;
        f32x2 qq0 = {q0, q0}, qq1 = {q1, q1};
        acc01 = __builtin_elementwise_fma(qq0, a001, acc01);
        acc23 = __builtin_elementwise_fma(qq0, a023, acc23);
        acc01 = __builtin_elementwise_fma(qq1, a101, acc01);
        acc23 = __builtin_elementwise_fma(qq1, a123, acc23);
    }
    float inv = 1.f / (d + 1e-16f);
    f32x2 b01 = ((const f32x2*)b2)[2 * g], b23 = ((const f32x2*)b2)[2 * g + 1];
    float vx = fmaxf(fmaf(acc01.x, inv, b01.x), 0.f);
    float vy = fmaxf(fmaf(acc01.y, inv, b01.y), 0.f);
    float vz = fmaxf(fmaf(acc23.x, inv, b23.x), 0.f);
    float vw = fmaxf(fmaf(acc23.y, inv, b23.y), 0.f);
    int b = batch[i];
    float* o = pool + (size_t)b * D_H + g * 4;
    atomicAdd(o + 0, vx);
    atomicAdd(o + 1, vy);
    atomicAdd(o + 2, vz);
    atomicAdd(o + 3, vw);
    if (g == 0) atomicAdd(&cnt[b], 1.0f);
}

// ---- mean, sigmoid, final FC ----
__global__ void k_final(const float* __restrict__ pool, const float* __restrict__ cnt,
                        const float* __restrict__ Wfc, const float* __restrict__ bfc,
                        float* __restrict__ out)
{
    int b = blockIdx.x * blockDim.x + threadIdx.x;
    if (b >= N_GRAPHS) return;
    float c = cnt[b]; c = c > 1.f ? c : 1.f;
    float acc = 0.f;
    #pragma unroll
    for (int j = 0; j < D_H; ++j) {
        float f = pool[b * D_H + j] / c;
        f = 1.f / (1.f + __expf(-f));
        acc = fmaf(f, Wfc[j], acc);
    }
    out[b] = acc + bfc[0];
}

extern "C" void kernel_launch(void* const* d_in, const int* in_sizes, int n_in,
                              void* d_out, int out_size, void* d_ws, size_t ws_size,
                              hipStream_t stream)
{
    const float* x    = (const float*)d_in[0];
    const int*   ei   = (const int*)  d_in[1];
    const int*   batch= (const int*)  d_in[2];
    const float* ew   = (const float*)d_in[3];
    const float* Wl1  = (const float*)d_in[4];
    const float* Wr1  = (const float*)d_in[5];
    const float* We1  = (const float*)d_in[6];
    const float* att1 = (const float*)d_in[7];
    const float* b1   = (const float*)d_in[8];
    const float* Wl2  = (const float*)d_in[9];
    const float* Wr2  = (const float*)d_in[10];
    const float* We2  = (const float*)d_in[11];
    const float* att2 = (const float*)d_in[12];
    const float* b2   = (const float*)d_in[13];
    const float* Wfc  = (const float*)d_in[14];
    const float* bfc  = (const float*)d_in[15];
    float* out = (float*)d_out;

    float* ws = (float*)d_ws;
    size_t off = 0;
    auto take = [&](size_t n) -> float* {
        float* p = ws + off;
        off = (off + n + 63) & ~(size_t)63;
        return p;
    };
    // --- zero-initialized region ---
    float* fillsum = take(1);
    int*   deg  = (int*)take(N_NODES);
    float* cnt  = take(N_GRAPHS);
    float* pool = take((size_t)N_GRAPHS * D_H);
    size_t zero_elems = off;
    // --- written-before-read buffers ---
    int*   start = (int*)take(N_NODES);
    int*   rank  = (int*)take(E_TOT);
    int*   bsum  = (int*)take(256);
    int2*  csr   = (int2*)take((size_t)(E_TOT + 8) * 2);
    unsigned short* Wt1  = (unsigned short*)take(512 * 128 / 2);
    unsigned short* Wt2  = (unsigned short*)take(64 * 256 / 2);
    unsigned short* xlr1 = (unsigned short*)take((size_t)N_NODES * 512 / 2);
    unsigned short* out1 = (unsigned short*)take((size_t)N_NODES * 256 / 2);
    unsigned short* xlr2 = (unsigned short*)take((size_t)N_NODES * 64 / 2);
    (void)ws_size; (void)in_sizes; (void)n_in; (void)out_size;

    hipMemsetAsync(d_ws, 0, zero_elems * sizeof(float), stream);

    // front: fill-value sum + degree histogram (captures rank) + weight panels
    k_front<<<RS_BLK + HIST_BLK + W1_BLK + W2_BLK, 256, 0, stream>>>(
        ew, ei, Wl1, Wr1, Wl2, Wr2, fillsum, deg, rank, Wt1, Wt2);

    // 3-kernel scan (scan3 writes csr slack entries)
    k_scan1<<<NSCAN_BLK, 256, 0, stream>>>(deg, start, bsum);
    k_scan2<<<1, 256, 0, stream>>>(bsum, NSCAN_BLK);
    k_scan3<<<NSCAN_BLK, 256, 0, stream>>>(start, bsum, csr);

    // hybrid: layer-1 projection (fused cast) || atomic-free CSR scatter
    k_gemm1_scatter<<<HY_TOT, 256, 0, stream>>>(
        x, Wt1, xlr1, ei, ew, fillsum, start, rank, csr);

    // fused layer-1 edge phase
    k_gat1<<<(N_NODES * 64 + 255) / 256, 256, 0, stream>>>(
        xlr1, start, deg, csr, We1, att1, b1, out1);

    // layer-2 projection: xlr2 = out1 @ [Wl2|Wr2]
    k_gemm2<<<dim3(1, (N_NODES + 63) / 64), 256, 0, stream>>>(
        out1, Wt2, xlr2, N_NODES);

    // fused layer-2 edge phase + pooling (8 threads per node)
    k_gat2<<<((size_t)N_NODES * 8 + 255) / 256, 256, 0, stream>>>(
        xlr2, start, deg, csr, We2, att2, b2, batch, pool, cnt);

    // final FC
    k_final<<<(N_GRAPHS + 255) / 256, 256, 0, stream>>>(pool, cnt, Wfc, bfc, out);
}